// Round 11
// baseline (374.797 us; speedup 1.0000x reference)
//
#include <hip/hip_runtime.h>

#define DIM 512
#define BATCH 65536
#define BM 32
#define THREADS 512
#define TILES 4
#define NBLK (BATCH / (BM * TILES))   // 512 blocks

typedef float f32x4 __attribute__((ext_vector_type(4)));
typedef float f32x16 __attribute__((ext_vector_type(16)));
typedef __bf16 bf16x8 __attribute__((ext_vector_type(8)));

__device__ __forceinline__ unsigned f2bf(float f) {
    unsigned u = __float_as_uint(f);
    return (u + 0x7FFFu + ((u >> 16) & 1u)) >> 16;
}

// Sf in MFMA-B-fragment order: Sf[((k0*16 + np)*64 + lane)*8 + j]
//   = bf16( A[n][k] + A[k][n] ),  n = np*32 + (lane&31),  k = k0*16 + (lane>>5)*8 + j
__global__ void prep_Sfrag(const float* __restrict__ A, unsigned short* __restrict__ Sf) {
    int idx = blockIdx.x * 256 + threadIdx.x;    // 0..32767 : (k0, np, lane)
    int lane = idx & 63;
    int np   = (idx >> 6) & 15;
    int k0   = idx >> 10;
    int n     = np * 32 + (lane & 31);
    int kbase = k0 * 16 + (lane >> 5) * 8;
    unsigned short tmp[8];
    #pragma unroll
    for (int j = 0; j < 8; ++j) {
        int k = kbase + j;
        tmp[j] = (unsigned short)f2bf(A[n * DIM + k] + A[k * DIM + n]);
    }
    *(uint4*)(Sf + (size_t)idx * 8) = *(const uint4*)tmp;
}

// out[b][0:512] = p[b] + q[b].S ; out[b][512:1024] = q[b]
// R9 schedule, longhand: named registers + macros only (no lambdas/arrays,
// which R7/R8/R10 showed defeat SROA and spill to scratch).
__global__ __launch_bounds__(THREADS, 4)
void gemm_kernel(const float* __restrict__ pq,
                 const unsigned short* __restrict__ Sf,
                 float* __restrict__ out) {
    __shared__ __align__(16) unsigned short qh0[BM * 256];  // 16 KB bf16 half-K buf A
    __shared__ __align__(16) unsigned short qh1[BM * 256];  // 16 KB bf16 half-K buf B
    __shared__ float sc[BM * 256];                          // 32 KB epilogue scratch
    const int tid  = threadIdx.x;
    const int wid  = tid >> 6;
    const int lane = tid & 63;
    const int row  = lane & 31;
    const int khalf = lane >> 5;
    const int rb = blockIdx.x * (BM * TILES);
    const unsigned short* Sfp = Sf + ((size_t)(wid * 2) * 64 + lane) * 8;

    // staging slot geometry (2 slots/thread); (512+tid)&31 == tid&31
    const int r0 = tid >> 5,              c80 = tid & 31;
    const int r1 = (THREADS + tid) >> 5,  c81 = tid & 31;
    const int wbo0 = r0 * 512 + ((c80 * 16) ^ ((r0 & 7) << 4));
    const int wbo1 = r1 * 512 + ((c81 * 16) ^ ((r1 & 7) << 4));

    f32x4 stg0, stg1, stg2, stg3;
    f32x4 pv0, pv1, pv2, pv3, pv4, pv5, pv6, pv7;
    f32x16 acc0, acc1;

#define Q_OFF(tile, half, rr, cc8) \
    ((size_t)(rb + (tile) * BM + (rr)) * 1024 + 512 + (half) * 256 + (cc8) * 8)

#define ISSUE_Q(tile, half) do { \
    stg0 = __builtin_nontemporal_load((const f32x4*)(pq + Q_OFF(tile, half, r0, c80)));     \
    stg1 = __builtin_nontemporal_load((const f32x4*)(pq + Q_OFF(tile, half, r0, c80) + 4)); \
    stg2 = __builtin_nontemporal_load((const f32x4*)(pq + Q_OFF(tile, half, r1, c81)));     \
    stg3 = __builtin_nontemporal_load((const f32x4*)(pq + Q_OFF(tile, half, r1, c81) + 4)); \
} while (0)

#define WRITE_BACK(tile, half, dst) do { \
    size_t g0_ = Q_OFF(tile, half, r0, c80), g1_ = Q_OFF(tile, half, r1, c81); \
    __builtin_nontemporal_store(stg0, (f32x4*)(out + g0_));     \
    __builtin_nontemporal_store(stg1, (f32x4*)(out + g0_ + 4)); \
    __builtin_nontemporal_store(stg2, (f32x4*)(out + g1_));     \
    __builtin_nontemporal_store(stg3, (f32x4*)(out + g1_ + 4)); \
    *(uint4*)((char*)(dst) + wbo0) = make_uint4( \
        f2bf(stg0.x) | (f2bf(stg0.y) << 16), f2bf(stg0.z) | (f2bf(stg0.w) << 16), \
        f2bf(stg1.x) | (f2bf(stg1.y) << 16), f2bf(stg1.z) | (f2bf(stg1.w) << 16)); \
    *(uint4*)((char*)(dst) + wbo1) = make_uint4( \
        f2bf(stg2.x) | (f2bf(stg2.y) << 16), f2bf(stg2.z) | (f2bf(stg2.w) << 16), \
        f2bf(stg3.x) | (f2bf(stg3.y) << 16), f2bf(stg3.z) | (f2bf(stg3.w) << 16)); \
} while (0)

// epilogue/p-prefetch address pieces, j = 0..3 (c = tid + j*512)
#define EJ(j)    (tid + (j) * 512)
#define EROW(j)  (EJ(j) >> 6)
#define ECC(j)   (EJ(j) & 63)
#define EGCOL(j) (((ECC(j) >> 3) * 64) + ((ECC(j) & 7) * 4))
#define ESCO(j)  (EROW(j) * 256 + ECC(j) * 4)
#define P_OFF(tb, j, pass) ((size_t)((tb) + EROW(j)) * 1024 + EGCOL(j) + (pass) * 32)

#define PREFETCH_P(tile) do { int tb_ = rb + (tile) * BM; \
    pv0 = __builtin_nontemporal_load((const f32x4*)(pq + P_OFF(tb_, 0, 0))); \
    pv1 = __builtin_nontemporal_load((const f32x4*)(pq + P_OFF(tb_, 1, 0))); \
    pv2 = __builtin_nontemporal_load((const f32x4*)(pq + P_OFF(tb_, 2, 0))); \
    pv3 = __builtin_nontemporal_load((const f32x4*)(pq + P_OFF(tb_, 3, 0))); \
    pv4 = __builtin_nontemporal_load((const f32x4*)(pq + P_OFF(tb_, 0, 1))); \
    pv5 = __builtin_nontemporal_load((const f32x4*)(pq + P_OFF(tb_, 1, 1))); \
    pv6 = __builtin_nontemporal_load((const f32x4*)(pq + P_OFF(tb_, 2, 1))); \
    pv7 = __builtin_nontemporal_load((const f32x4*)(pq + P_OFF(tb_, 3, 1))); \
} while (0)

#define KHALF(buf, half) do { \
    const unsigned short* sp_ = Sfp + (size_t)(half) * 16 * 8192; \
    bf16x8 b0c = *(const bf16x8*)(sp_);       \
    bf16x8 b1c = *(const bf16x8*)(sp_ + 512); \
    _Pragma("unroll") \
    for (int k = 0; k < 16; ++k) { \
        bf16x8 b0n, b1n; \
        if (k < 15) { \
            b0n = *(const bf16x8*)(sp_ + (size_t)(k + 1) * 8192);       \
            b1n = *(const bf16x8*)(sp_ + (size_t)(k + 1) * 8192 + 512); \
        } \
        int bo_ = row * 512 + ((k * 32 + khalf * 16) ^ ((row & 7) << 4)); \
        bf16x8 a_ = *(const bf16x8*)((const char*)(buf) + bo_); \
        acc0 = __builtin_amdgcn_mfma_f32_32x32x16_bf16(a_, b0c, acc0, 0, 0, 0); \
        acc1 = __builtin_amdgcn_mfma_f32_32x32x16_bf16(a_, b1c, acc1, 0, 0, 0); \
        if (k < 15) { b0c = b0n; b1c = b1n; } \
    } \
} while (0)

#define EPI_PASS(tb, ac, pA, pB, pC, pD, pass) do { \
    _Pragma("unroll") \
    for (int reg = 0; reg < 16; ++reg) { \
        int r_ = (reg & 3) + 8 * (reg >> 2) + 4 * khalf; \
        sc[r_ * 256 + wid * 32 + row] = (ac)[reg];   /* 2-way bank alias: free */ \
    } \
    __syncthreads(); \
    __builtin_nontemporal_store((pA) + *(const f32x4*)(sc + ESCO(0)), (f32x4*)(out + P_OFF(tb, 0, pass))); \
    __builtin_nontemporal_store((pB) + *(const f32x4*)(sc + ESCO(1)), (f32x4*)(out + P_OFF(tb, 1, pass))); \
    __builtin_nontemporal_store((pC) + *(const f32x4*)(sc + ESCO(2)), (f32x4*)(out + P_OFF(tb, 2, pass))); \
    __builtin_nontemporal_store((pD) + *(const f32x4*)(sc + ESCO(3)), (f32x4*)(out + P_OFF(tb, 3, pass))); \
    __syncthreads(); \
} while (0)

    // prologue: tile 0 half 0, synchronous
    ISSUE_Q(0, 0);
    WRITE_BACK(0, 0, qh0);
    __syncthreads();

    for (int t = 0; t < TILES; ++t) {
        acc0 = f32x16{};
        acc1 = f32x16{};
        // even phase: p-prefetch (lands by epilogue), q(t,1) in flight over k-half 0
        PREFETCH_P(t);
        ISSUE_Q(t, 1);
        KHALF(qh0, 0);
        WRITE_BACK(t, 1, qh1);
        __syncthreads();
        // odd phase: q(t+1,0) in flight over k-half 1
        if (t + 1 < TILES) ISSUE_Q(t + 1, 0);
        KHALF(qh1, 1);
        if (t + 1 < TILES) WRITE_BACK(t + 1, 0, qh0);
        __syncthreads();
        // epilogue: pure stores, p already in registers
        int tb = rb + t * BM;
        EPI_PASS(tb, acc0, pv0, pv1, pv2, pv3, 0);
        EPI_PASS(tb, acc1, pv4, pv5, pv6, pv7, 1);
    }
}

extern "C" void kernel_launch(void* const* d_in, const int* in_sizes, int n_in,
                              void* d_out, int out_size, void* d_ws, size_t ws_size,
                              hipStream_t stream) {
    const float* pq = (const float*)d_in[0];
    const float* A  = (const float*)d_in[1];
    float* out = (float*)d_out;
    unsigned short* Sf = (unsigned short*)d_ws;   // 512 KB fragment-ordered S

    prep_Sfrag<<<128, 256, 0, stream>>>(A, Sf);
    gemm_kernel<<<NBLK, THREADS, 0, stream>>>(pq, Sf, out);
}

// Round 12
// 156.223 us; speedup vs baseline: 2.3991x; 2.3991x over previous
//
#include <hip/hip_runtime.h>

#define DIM 512
#define BATCH 65536
#define BM 32
#define THREADS 512
#define TILES 4
#define NBLK (BATCH / (BM * TILES))   // 512 blocks

typedef float f32x4 __attribute__((ext_vector_type(4)));
typedef float f32x16 __attribute__((ext_vector_type(16)));
typedef __bf16 bf16x8 __attribute__((ext_vector_type(8)));

__device__ __forceinline__ unsigned f2bf(float f) {
    unsigned u = __float_as_uint(f);
    return (u + 0x7FFFu + ((u >> 16) & 1u)) >> 16;
}

// Sf in MFMA-B-fragment order: Sf[((k0*16 + np)*64 + lane)*8 + j]
//   = bf16( A[n][k] + A[k][n] ),  n = np*32 + (lane&31),  k = k0*16 + (lane>>5)*8 + j
__global__ void prep_Sfrag(const float* __restrict__ A, unsigned short* __restrict__ Sf) {
    int idx = blockIdx.x * 256 + threadIdx.x;    // 0..32767 : (k0, np, lane)
    int lane = idx & 63;
    int np   = (idx >> 6) & 15;
    int k0   = idx >> 10;
    int n     = np * 32 + (lane & 31);
    int kbase = k0 * 16 + (lane >> 5) * 8;
    unsigned short tmp[8];
    #pragma unroll
    for (int j = 0; j < 8; ++j) {
        int k = kbase + j;
        tmp[j] = (unsigned short)f2bf(A[n * DIM + k] + A[k * DIM + n]);
    }
    *(uint4*)(Sf + (size_t)idx * 8) = *(const uint4*)tmp;
}

// out[b][0:512] = p[b] + q[b].S ; out[b][512:1024] = q[b]
// R9 phase-pipelined structure; changes vs R9: (1) depth-4 B prefetch in the
// k-half loop, (2) 16-slot XOR swizzle (was 8 -> 4-way ds_read conflict).
__global__ __launch_bounds__(THREADS, 4)
void gemm_kernel(const float* __restrict__ pq,
                 const unsigned short* __restrict__ Sf,
                 float* __restrict__ out) {
    __shared__ __align__(16) unsigned short qh[2][BM * 256];  // 2 x 16 KB bf16 half-K
    __shared__ float sc[BM * 256];                            // 32 KB epilogue scratch
    const int tid  = threadIdx.x;
    const int wid  = tid >> 6;
    const int lane = tid & 63;
    const int row  = lane & 31;
    const int khalf = lane >> 5;
    const int rb = blockIdx.x * (BM * TILES);
    const unsigned short* Sfp = Sf + ((size_t)(wid * 2) * 64 + lane) * 8;

    f32x4 stg[4];   // staged q for the next phase (consumed within one phase)

    auto issue_loads = [&](int ph) {
        int tile = ph >> 1, half = ph & 1;
        #pragma unroll
        for (int i = 0; i < 2; ++i) {
            int slot = i * THREADS + tid;
            int r = slot >> 5, c8 = slot & 31;
            size_t g = (size_t)(rb + tile * BM + r) * 1024 + 512 + half * 256 + c8 * 8;
            stg[2*i]   = __builtin_nontemporal_load((const f32x4*)(pq + g));
            stg[2*i+1] = __builtin_nontemporal_load((const f32x4*)(pq + g + 4));
        }
    };
    auto write_back = [&](int ph) {
        int tile = ph >> 1, half = ph & 1;
        unsigned short* dst = qh[ph & 1];
        #pragma unroll
        for (int i = 0; i < 2; ++i) {
            int slot = i * THREADS + tid;
            int r = slot >> 5, c8 = slot & 31;
            size_t g = (size_t)(rb + tile * BM + r) * 1024 + 512 + half * 256 + c8 * 8;
            __builtin_nontemporal_store(stg[2*i],   (f32x4*)(out + g));     // q passthrough
            __builtin_nontemporal_store(stg[2*i+1], (f32x4*)(out + g + 4));
            unsigned u0 = f2bf(stg[2*i].x)   | (f2bf(stg[2*i].y)   << 16);
            unsigned u1 = f2bf(stg[2*i].z)   | (f2bf(stg[2*i].w)   << 16);
            unsigned u2 = f2bf(stg[2*i+1].x) | (f2bf(stg[2*i+1].y) << 16);
            unsigned u3 = f2bf(stg[2*i+1].z) | (f2bf(stg[2*i+1].w) << 16);
            int b = r * 512 + ((c8 * 16) ^ ((r & 15) << 4));   // 16-slot swizzle
            *(uint4*)((char*)dst + b) = make_uint4(u0, u1, u2, u3);
        }
    };
    auto khalf_loop = [&](int ph, f32x16& acc0, f32x16& acc1) {
        int half = ph & 1;
        const unsigned short* buf = qh[ph & 1];
        const unsigned short* sp = Sfp + (size_t)(half * 16) * 8192;
        // depth-4 rotating B pipeline: slots A,B,C,D hold k, k+1, k+2, k+3
        bf16x8 b0A, b1A, b0B, b1B, b0C, b1C, b0D, b1D;
        b0A = *(const bf16x8*)(sp);                 b1A = *(const bf16x8*)(sp + 512);
        b0B = *(const bf16x8*)(sp + 1*8192);        b1B = *(const bf16x8*)(sp + 1*8192 + 512);
        b0C = *(const bf16x8*)(sp + 2*8192);        b1C = *(const bf16x8*)(sp + 2*8192 + 512);
#define KSTEP(k, bL0, bL1, bU0, bU1) do { \
        if ((k) + 3 < 16) { \
            bL0 = *(const bf16x8*)(sp + (size_t)((k) + 3) * 8192);       \
            bL1 = *(const bf16x8*)(sp + (size_t)((k) + 3) * 8192 + 512); \
        } \
        int bo_ = row * 512 + (((k) * 32 + khalf * 16) ^ ((row & 15) << 4)); \
        bf16x8 a_ = *(const bf16x8*)((const char*)buf + bo_); \
        acc0 = __builtin_amdgcn_mfma_f32_32x32x16_bf16(a_, bU0, acc0, 0, 0, 0); \
        acc1 = __builtin_amdgcn_mfma_f32_32x32x16_bf16(a_, bU1, acc1, 0, 0, 0); \
    } while (0)
        KSTEP( 0, b0D, b1D, b0A, b1A);
        KSTEP( 1, b0A, b1A, b0B, b1B);
        KSTEP( 2, b0B, b1B, b0C, b1C);
        KSTEP( 3, b0C, b1C, b0D, b1D);
        KSTEP( 4, b0D, b1D, b0A, b1A);
        KSTEP( 5, b0A, b1A, b0B, b1B);
        KSTEP( 6, b0B, b1B, b0C, b1C);
        KSTEP( 7, b0C, b1C, b0D, b1D);
        KSTEP( 8, b0D, b1D, b0A, b1A);
        KSTEP( 9, b0A, b1A, b0B, b1B);
        KSTEP(10, b0B, b1B, b0C, b1C);
        KSTEP(11, b0C, b1C, b0D, b1D);
        KSTEP(12, b0D, b1D, b0A, b1A);
        KSTEP(13, b0A, b1A, b0B, b1B);
        KSTEP(14, b0B, b1B, b0C, b1C);
        KSTEP(15, b0C, b1C, b0D, b1D);
#undef KSTEP
    };
    auto epilogue = [&](int tile, const f32x16& acc0, const f32x16& acc1) {
        int tb = rb + tile * BM;
        #pragma unroll
        for (int pass = 0; pass < 2; ++pass) {
            const f32x16& ac = pass ? acc1 : acc0;
            #pragma unroll
            for (int reg = 0; reg < 16; ++reg) {
                int r = (reg & 3) + 8 * (reg >> 2) + 4 * khalf;
                sc[r * 256 + wid * 32 + row] = ac[reg];   // 2-way bank alias: free
            }
            __syncthreads();
            #pragma unroll
            for (int j = 0; j < 4; ++j) {
                int c = tid + j * 512;
                int r = c >> 6, cc = c & 63;
                int gcol = (cc >> 3) * 64 + (cc & 7) * 4 + pass * 32;
                size_t g = (size_t)(tb + r) * 1024 + gcol;
                f32x4 v  = *(const f32x4*)(sc + r * 256 + cc * 4);
                f32x4 pv = __builtin_nontemporal_load((const f32x4*)(pq + g));
                __builtin_nontemporal_store(pv + v, (f32x4*)(out + g));
            }
            __syncthreads();
        }
    };

    f32x16 acc0, acc1;
    // prologue: phase 0 synchronous
    issue_loads(0);
    write_back(0);
    __syncthreads();

    for (int ph = 0; ph < 2 * TILES; ++ph) {
        if ((ph & 1) == 0) { acc0 = f32x16{}; acc1 = f32x16{}; }
        if (ph + 1 < 2 * TILES) issue_loads(ph + 1);     // in flight across k-half
        khalf_loop(ph, acc0, acc1);
        if (ph + 1 < 2 * TILES) write_back(ph + 1);      // passthrough + LDS fill
        __syncthreads();
        if (ph & 1) epilogue(ph >> 1, acc0, acc1);
    }
}

extern "C" void kernel_launch(void* const* d_in, const int* in_sizes, int n_in,
                              void* d_out, int out_size, void* d_ws, size_t ws_size,
                              hipStream_t stream) {
    const float* pq = (const float*)d_in[0];
    const float* A  = (const float*)d_in[1];
    float* out = (float*)d_out;
    unsigned short* Sf = (unsigned short*)d_ws;   // 512 KB fragment-ordered S

    prep_Sfrag<<<128, 256, 0, stream>>>(A, Sf);
    gemm_kernel<<<NBLK, THREADS, 0, stream>>>(pq, Sf, out);
}

// Round 13
// 135.560 us; speedup vs baseline: 2.7648x; 1.1524x over previous
//
#include <hip/hip_runtime.h>

#define DIM 512
#define BATCH 65536
#define BM 32
#define THREADS 512
#define TILES 4
#define NBLK (BATCH / (BM * TILES))   // 512 blocks

typedef float f32x4 __attribute__((ext_vector_type(4)));
typedef float f32x16 __attribute__((ext_vector_type(16)));
typedef __bf16 bf16x8 __attribute__((ext_vector_type(8)));

__device__ __forceinline__ unsigned f2bf(float f) {
    unsigned u = __float_as_uint(f);
    return (u + 0x7FFFu + ((u >> 16) & 1u)) >> 16;
}

// LDS-only barrier: all barriers in this kernel guard LDS traffic exclusively
// (qh write->read, sc write->read). __syncthreads() would emit
// s_waitcnt vmcnt(0) lgkmcnt(0), draining in-flight NT store ACKs and the
// cross-phase q prefetch at every barrier (T4: never drain vmcnt in-loop).
__device__ __forceinline__ void lbar() {
    asm volatile("s_waitcnt lgkmcnt(0)" ::: "memory");
    __builtin_amdgcn_s_barrier();
    __builtin_amdgcn_sched_barrier(0);   // lesson #18: no hoisting past the wait
}

// Sf in MFMA-B-fragment order: Sf[((k0*16 + np)*64 + lane)*8 + j]
//   = bf16( A[n][k] + A[k][n] ),  n = np*32 + (lane&31),  k = k0*16 + (lane>>5)*8 + j
__global__ void prep_Sfrag(const float* __restrict__ A, unsigned short* __restrict__ Sf) {
    int idx = blockIdx.x * 256 + threadIdx.x;    // 0..32767 : (k0, np, lane)
    int lane = idx & 63;
    int np   = (idx >> 6) & 15;
    int k0   = idx >> 10;
    int n     = np * 32 + (lane & 31);
    int kbase = k0 * 16 + (lane >> 5) * 8;
    unsigned short tmp[8];
    #pragma unroll
    for (int j = 0; j < 8; ++j) {
        int k = kbase + j;
        tmp[j] = (unsigned short)f2bf(A[n * DIM + k] + A[k * DIM + n]);
    }
    *(uint4*)(Sf + (size_t)idx * 8) = *(const uint4*)tmp;
}

// out[b][0:512] = p[b] + q[b].S ; out[b][512:1024] = q[b]
// R9 phase-pipelined structure, LDS-only barriers.
__global__ __launch_bounds__(THREADS, 4)
void gemm_kernel(const float* __restrict__ pq,
                 const unsigned short* __restrict__ Sf,
                 float* __restrict__ out) {
    __shared__ __align__(16) unsigned short qh[2][BM * 256];  // 2 x 16 KB bf16 half-K
    __shared__ float sc[BM * 256];                            // 32 KB epilogue scratch
    const int tid  = threadIdx.x;
    const int wid  = tid >> 6;
    const int lane = tid & 63;
    const int row  = lane & 31;
    const int khalf = lane >> 5;
    const int rb = blockIdx.x * (BM * TILES);
    const unsigned short* Sfp = Sf + ((size_t)(wid * 2) * 64 + lane) * 8;

    f32x4 stg[4];   // staged q for the next phase (consumed within one phase)

    auto issue_loads = [&](int ph) {
        int tile = ph >> 1, half = ph & 1;
        #pragma unroll
        for (int i = 0; i < 2; ++i) {
            int slot = i * THREADS + tid;
            int r = slot >> 5, c8 = slot & 31;
            size_t g = (size_t)(rb + tile * BM + r) * 1024 + 512 + half * 256 + c8 * 8;
            stg[2*i]   = __builtin_nontemporal_load((const f32x4*)(pq + g));
            stg[2*i+1] = __builtin_nontemporal_load((const f32x4*)(pq + g + 4));
        }
    };
    auto write_back = [&](int ph) {
        int tile = ph >> 1, half = ph & 1;
        unsigned short* dst = qh[ph & 1];
        #pragma unroll
        for (int i = 0; i < 2; ++i) {
            int slot = i * THREADS + tid;
            int r = slot >> 5, c8 = slot & 31;
            size_t g = (size_t)(rb + tile * BM + r) * 1024 + 512 + half * 256 + c8 * 8;
            __builtin_nontemporal_store(stg[2*i],   (f32x4*)(out + g));     // q passthrough
            __builtin_nontemporal_store(stg[2*i+1], (f32x4*)(out + g + 4));
            unsigned u0 = f2bf(stg[2*i].x)   | (f2bf(stg[2*i].y)   << 16);
            unsigned u1 = f2bf(stg[2*i].z)   | (f2bf(stg[2*i].w)   << 16);
            unsigned u2 = f2bf(stg[2*i+1].x) | (f2bf(stg[2*i+1].y) << 16);
            unsigned u3 = f2bf(stg[2*i+1].z) | (f2bf(stg[2*i+1].w) << 16);
            int b = r * 512 + ((c8 * 16) ^ ((r & 7) << 4));
            *(uint4*)((char*)dst + b) = make_uint4(u0, u1, u2, u3);
        }
    };
    auto khalf_loop = [&](int ph, f32x16& acc0, f32x16& acc1) {
        int half = ph & 1;
        const unsigned short* buf = qh[ph & 1];
        const unsigned short* sp = Sfp + (size_t)(half * 16) * 8192;
        bf16x8 b0_c = *(const bf16x8*)(sp);
        bf16x8 b1_c = *(const bf16x8*)(sp + 512);
        #pragma unroll
        for (int k = 0; k < 16; ++k) {
            bf16x8 b0_n, b1_n;
            if (k < 15) {
                b0_n = *(const bf16x8*)(sp + (size_t)(k + 1) * 8192);
                b1_n = *(const bf16x8*)(sp + (size_t)(k + 1) * 8192 + 512);
            }
            int b = row * 512 + ((k * 32 + khalf * 16) ^ ((row & 7) << 4));
            bf16x8 a = *(const bf16x8*)((const char*)buf + b);
            acc0 = __builtin_amdgcn_mfma_f32_32x32x16_bf16(a, b0_c, acc0, 0, 0, 0);
            acc1 = __builtin_amdgcn_mfma_f32_32x32x16_bf16(a, b1_c, acc1, 0, 0, 0);
            if (k < 15) { b0_c = b0_n; b1_c = b1_n; }
        }
    };
    auto epilogue = [&](int tile, const f32x16& acc0, const f32x16& acc1) {
        int tb = rb + tile * BM;
        #pragma unroll
        for (int pass = 0; pass < 2; ++pass) {
            const f32x16& ac = pass ? acc1 : acc0;
            #pragma unroll
            for (int reg = 0; reg < 16; ++reg) {
                int r = (reg & 3) + 8 * (reg >> 2) + 4 * khalf;
                sc[r * 256 + wid * 32 + row] = ac[reg];   // 2-way bank alias: free
            }
            lbar();
            #pragma unroll
            for (int j = 0; j < 4; ++j) {
                int c = tid + j * 512;
                int r = c >> 6, cc = c & 63;
                int gcol = (cc >> 3) * 64 + (cc & 7) * 4 + pass * 32;
                size_t g = (size_t)(tb + r) * 1024 + gcol;
                f32x4 v  = *(const f32x4*)(sc + r * 256 + cc * 4);
                f32x4 pv = __builtin_nontemporal_load((const f32x4*)(pq + g));
                __builtin_nontemporal_store(pv + v, (f32x4*)(out + g));
            }
            lbar();
        }
    };

    f32x16 acc0, acc1;
    // prologue: phase 0 synchronous
    issue_loads(0);
    write_back(0);
    lbar();

    for (int ph = 0; ph < 2 * TILES; ++ph) {
        if ((ph & 1) == 0) { acc0 = f32x16{}; acc1 = f32x16{}; }
        if (ph + 1 < 2 * TILES) issue_loads(ph + 1);     // in flight across k-half
        khalf_loop(ph, acc0, acc1);
        if (ph + 1 < 2 * TILES) write_back(ph + 1);      // passthrough + LDS fill
        lbar();
        if (ph & 1) epilogue(ph >> 1, acc0, acc1);
    }
}

extern "C" void kernel_launch(void* const* d_in, const int* in_sizes, int n_in,
                              void* d_out, int out_size, void* d_ws, size_t ws_size,
                              hipStream_t stream) {
    const float* pq = (const float*)d_in[0];
    const float* A  = (const float*)d_in[1];
    float* out = (float*)d_out;
    unsigned short* Sf = (unsigned short*)d_ws;   // 512 KB fragment-ordered S

    prep_Sfrag<<<128, 256, 0, stream>>>(A, Sf);
    gemm_kernel<<<NBLK, THREADS, 0, stream>>>(pq, Sf, out);
}